// Round 13
// baseline (913.256 us; speedup 1.0000x reference)
//
// Round 13: round 12 with the launch-bounds fix. (1024, 4) was interpreted as
// min 4 BLOCKS/CU (CUDA semantics) -> 64-wave target -> VGPR clamped to 64 ->
// massive spills (FETCH_SIZE 44 MB -> 810 MB, dur 350 -> 812 us).
// (1024, 1) targets 1 block = 16 waves = 4 waves/SIMD -> VGPR cap 128 (r11's
// working set is 120). Everything else identical to round 12 (absmax 0.03125).
#include <hip/hip_runtime.h>
#include <math.h>

#define NN    16384
#define NB    8
#define HD    128
#define TILE  128
#define HALO  6
#define RWS   140     // TILE + 2*HALO (valid rows)
#define RWSP  144     // padded to 9 m-tiles of 16
#define PP    136     // bf16 pitch in shorts: 272 B/row, 16B-aligned

typedef short v8s __attribute__((ext_vector_type(8)));
typedef float v4f __attribute__((ext_vector_type(4)));

__device__ __forceinline__ unsigned short f2b(float x) {   // RNE, == v_cvt_bf16
  union { float f; unsigned u; } v; v.f = x;
  unsigned r = v.u + 0x7FFFu + ((v.u >> 16) & 1u);
  return (unsigned short)(r >> 16);
}
__device__ __forceinline__ float b2f(unsigned short u) {
  union { unsigned u; float f; } v; v.u = ((unsigned)u) << 16; return v.f;
}
// fast silu: v_exp_f32 + v_rcp_f32 (validated rounds 8/11)
__device__ __forceinline__ float silu_f(float z) {
  return z * __frcp_rn(1.0f + __expf(-z));
}
// 8 fp32 -> 8 bf16 via 4 hardware packed converts (RNE), union-punned
__device__ __forceinline__ v8s cvt8(const float* p) {
  union { v8s s; unsigned u[4]; } r;
#pragma unroll
  for (int q = 0; q < 4; ++q)
    asm("v_cvt_pk_bf16_f32 %0, %1, %2" : "=v"(r.u[q]) : "v"(p[2 * q]), "v"(p[2 * q + 1]));
  return r.s;
}

// MFMA GEMM, pure bf16: acc[mt][nt] += X[moff+mt*16+m][:] @ W[:][n]
// X: bf16 plane in LDS (pitch PP) -> 1x ds_read_b128 per fragment.
// W: fp32 in GLOBAL, row-major [128][128], cvt on the fly (4 cvt_pk/fragment).
template<int MT>
__device__ __forceinline__ void mgemm(const short* X, const float* __restrict__ W,
                                      int moff, int wn, int l15, int quad, v4f acc[][2]) {
  const int k0q = quad * 8;
  v8s wf[2][4];
#pragma unroll
  for (int nt = 0; nt < 2; ++nt) {
    const int n = wn * 32 + nt * 16 + l15;
#pragma unroll
    for (int ks = 0; ks < 4; ++ks) {
      float wv[8];
#pragma unroll
      for (int j = 0; j < 8; ++j) wv[j] = W[(ks * 32 + k0q + j) * HD + n];
      wf[nt][ks] = cvt8(wv);
    }
  }
#pragma unroll
  for (int ks = 0; ks < 4; ++ks) {
#pragma unroll
    for (int mt = 0; mt < MT; ++mt) {
      const int xo = (moff + mt * 16 + l15) * PP + ks * 32 + k0q;
      v8s a = *(const v8s*)&X[xo];
#pragma unroll
      for (int nt = 0; nt < 2; ++nt)
        acc[mt][nt] = __builtin_amdgcn_mfma_f32_16x16x32_bf16(a, wf[nt][ks], acc[mt][nt], 0, 0, 0);
    }
  }
}

__global__ __launch_bounds__(1024, 1) void gno_mfma(
    const float* __restrict__ h, const float* __restrict__ coord,
    const float* __restrict__ msg_w1, const float* __restrict__ msg_b1,
    const float* __restrict__ msg_w2, const float* __restrict__ msg_b2,
    const float* __restrict__ upd_w1, const float* __restrict__ upd_b1,
    const float* __restrict__ upd_w2, const float* __restrict__ upd_b2,
    const float* __restrict__ ln_g, const float* __restrict__ ln_b,
    float* __restrict__ out) {
  // LDS = 39168 + 39168 + 34816 + 34816 + 576 = 148544 B -> 1 WG/CU, 16 waves
  __shared__ short sHs[RWSP * PP];   // h bf16 (G1,G2,G4)
  __shared__ short sBs[RWSP * PP];   // B bf16 (G1->MSG), then dh bf16 (G5->LN)
  __shared__ short sP1[TILE * PP];   // A (G2->MSG), then agg (G3->G4)
  __shared__ short sP2[TILE * PP];   // s (MSG->G3), then t (G4->G5)
  __shared__ float sC[RWSP];         // coord

  const int t = threadIdx.x;
  const int wave = t >> 6, lane = t & 63, l15 = lane & 15, quad = lane >> 4;
  const int wn = wave & 3;            // column group: cols [wn*32, wn*32+32)
  const int wm = wave >> 2;           // row group: rows [wm*32, wm*32+32) of the tile
  const int b = blockIdx.x / (NN / TILE);
  const int n0 = (blockIdx.x % (NN / TILE)) * TILE;
  const size_t hb = ((size_t)b * NN + n0) * HD;
  const int col0 = wn * 32 + l15, col1 = col0 + 16;

  // ---- defensive zero-init of ALL LDS (barrier-fenced from staging) ----
  for (int e = t; e < RWSP * PP / 2; e += 1024) {
    ((int*)sHs)[e] = 0; ((int*)sBs)[e] = 0;
  }
  for (int e = t; e < TILE * PP / 2; e += 1024) {
    ((int*)sP1)[e] = 0; ((int*)sP2)[e] = 0;
  }
  __syncthreads();

  // ---- stage h -> bf16 plane (hardware cvt_pk); zero-fill OOB rows ----
  for (int e = t; e < RWSP * HD / 4; e += 1024) {  // 4608 quads
    const int r = e >> 5, c4 = (e & 31) << 2;
    const int g = n0 - HALO + r;
    float4 v = {0.f, 0.f, 0.f, 0.f};
    if (g >= 0 && g < NN) v = *(const float4*)&h[((size_t)b * NN + g) * HD + c4];
    unsigned h01, h23;
    asm("v_cvt_pk_bf16_f32 %0, %1, %2" : "=v"(h01) : "v"(v.x), "v"(v.y));
    asm("v_cvt_pk_bf16_f32 %0, %1, %2" : "=v"(h23) : "v"(v.z), "v"(v.w));
    *(uint2*)&sHs[r * PP + c4] = make_uint2(h01, h23);
  }
  if (t < RWSP) {
    const int g = n0 - HALO + t;
    sC[t] = (g >= 0 && g < NN) ? coord[(size_t)b * NN + g] : 0.f;
  }
  __syncthreads();

  // ---- G1 (MFMA): B = sH(144 rows) @ msg_w1[128:256] -> sBs bf16 ----
  // 9 m-tiles split 3+2+2+2 across the 4 row-groups.
  if (wm == 0) {
    v4f acc[3][2];
#pragma unroll
    for (int mt = 0; mt < 3; ++mt)
#pragma unroll
      for (int nt = 0; nt < 2; ++nt) acc[mt][nt] = (v4f){0.f, 0.f, 0.f, 0.f};
    mgemm<3>(sHs, msg_w1 + 128 * HD, 0, wn, l15, quad, acc);
#pragma unroll
    for (int mt = 0; mt < 3; ++mt)
#pragma unroll
      for (int nt = 0; nt < 2; ++nt)
#pragma unroll
        for (int rg = 0; rg < 4; ++rg)
          sBs[(mt * 16 + quad * 4 + rg) * PP + wn * 32 + nt * 16 + l15] =
              (short)f2b(acc[mt][nt][rg]);
  } else {
    const int moff = 48 + (wm - 1) * 32;   // 48, 80, 112
    v4f acc[2][2];
#pragma unroll
    for (int mt = 0; mt < 2; ++mt)
#pragma unroll
      for (int nt = 0; nt < 2; ++nt) acc[mt][nt] = (v4f){0.f, 0.f, 0.f, 0.f};
    mgemm<2>(sHs, msg_w1 + 128 * HD, moff, wn, l15, quad, acc);
#pragma unroll
    for (int mt = 0; mt < 2; ++mt)
#pragma unroll
      for (int nt = 0; nt < 2; ++nt)
#pragma unroll
        for (int rg = 0; rg < 4; ++rg)
          sBs[(moff + mt * 16 + quad * 4 + rg) * PP + wn * 32 + nt * 16 + l15] =
              (short)f2b(acc[mt][nt][rg]);
  }
  // ---- G2 (MFMA): A = sH(tile rows) @ msg_w1[0:128] + b1 -> sP1 bf16 ----
  {
    v4f acc[2][2];
#pragma unroll
    for (int mt = 0; mt < 2; ++mt)
#pragma unroll
      for (int nt = 0; nt < 2; ++nt) acc[mt][nt] = (v4f){0.f, 0.f, 0.f, 0.f};
    mgemm<2>(sHs, msg_w1, HALO + wm * 32, wn, l15, quad, acc);
    float bv0 = msg_b1[col0], bv1 = msg_b1[col1];
#pragma unroll
    for (int mt = 0; mt < 2; ++mt)
#pragma unroll
      for (int nt = 0; nt < 2; ++nt)
#pragma unroll
        for (int rg = 0; rg < 4; ++rg)
          sP1[(wm * 32 + mt * 16 + quad * 4 + rg) * PP + wn * 32 + nt * 16 + l15] =
              (short)f2b(acc[mt][nt][rg] + (nt ? bv1 : bv0));
  }
  __syncthreads();

  // ---- MSG: s_i = (1/cnt) * sum silu(A_i + B_j + dc*w1_last) -> sP2 bf16 ----
  {
    const int c = t & 127;
    const int grp = t >> 7;   // 0..7 -> rows grp*16 .. grp*16+15
    const float wl = msg_w1[256 * HD + c];
    for (int rr = 0; rr < 16; ++rr) {
      const int r = grp * 16 + rr;
      const int i = n0 + r;
      const float a = b2f((unsigned short)sP1[r * PP + c]);
      const float ci = sC[r + HALO];
      float s = 0.f;
#pragma unroll
      for (int d = -HALO; d <= HALO; ++d) {
        if (d == 0) continue;
        const int j = i + d;
        if (j >= 0 && j < NN) {
          const int rj = r + HALO + d;
          const float z = a + b2f((unsigned short)sBs[rj * PP + c]) + (sC[rj] - ci) * wl;
          s += silu_f(z);
        }
      }
      const int cnt = min(i, HALO) + min(NN - 1 - i, HALO);
      sP2[r * PP + c] = (short)f2b(s / (float)cnt);
    }
  }
  __syncthreads();

  // ---- G3 (MFMA): agg = P2(s) @ msg_w2 + b2 -> sP1 (A dead) ----
  {
    v4f acc[2][2];
#pragma unroll
    for (int mt = 0; mt < 2; ++mt)
#pragma unroll
      for (int nt = 0; nt < 2; ++nt) acc[mt][nt] = (v4f){0.f, 0.f, 0.f, 0.f};
    mgemm<2>(sP2, msg_w2, wm * 32, wn, l15, quad, acc);
    float bv0 = msg_b2[col0], bv1 = msg_b2[col1];
#pragma unroll
    for (int mt = 0; mt < 2; ++mt)
#pragma unroll
      for (int nt = 0; nt < 2; ++nt)
#pragma unroll
        for (int rg = 0; rg < 4; ++rg)
          sP1[(wm * 32 + mt * 16 + quad * 4 + rg) * PP + wn * 32 + nt * 16 + l15] =
              (short)f2b(acc[mt][nt][rg] + (nt ? bv1 : bv0));
  }
  __syncthreads();

  // ---- G4 (MFMA): t = silu(sH@upd_w1[0:128] + P1(agg)@upd_w1[128:256] + ub1) -> sP2 ----
  {
    v4f acc[2][2];
#pragma unroll
    for (int mt = 0; mt < 2; ++mt)
#pragma unroll
      for (int nt = 0; nt < 2; ++nt) acc[mt][nt] = (v4f){0.f, 0.f, 0.f, 0.f};
    mgemm<2>(sHs, upd_w1, HALO + wm * 32, wn, l15, quad, acc);
    mgemm<2>(sP1, upd_w1 + 128 * HD, wm * 32, wn, l15, quad, acc);
    float bv0 = upd_b1[col0], bv1 = upd_b1[col1];
#pragma unroll
    for (int mt = 0; mt < 2; ++mt)
#pragma unroll
      for (int nt = 0; nt < 2; ++nt)
#pragma unroll
        for (int rg = 0; rg < 4; ++rg)
          sP2[(wm * 32 + mt * 16 + quad * 4 + rg) * PP + wn * 32 + nt * 16 + l15] =
              (short)f2b(silu_f(acc[mt][nt][rg] + (nt ? bv1 : bv0)));
  }
  __syncthreads();

  // ---- G5 (MFMA): dh = P2(t) @ upd_w2 + ub2 -> sBs bf16 rows 0..127 (B dead) ----
  {
    v4f acc[2][2];
#pragma unroll
    for (int mt = 0; mt < 2; ++mt)
#pragma unroll
      for (int nt = 0; nt < 2; ++nt) acc[mt][nt] = (v4f){0.f, 0.f, 0.f, 0.f};
    mgemm<2>(sP2, upd_w2, wm * 32, wn, l15, quad, acc);
    float bv0 = upd_b2[col0], bv1 = upd_b2[col1];
#pragma unroll
    for (int mt = 0; mt < 2; ++mt)
#pragma unroll
      for (int nt = 0; nt < 2; ++nt)
#pragma unroll
        for (int rg = 0; rg < 4; ++rg)
          sBs[(wm * 32 + mt * 16 + quad * 4 + rg) * PP + wn * 32 + nt * 16 + l15] =
              (short)f2b(acc[mt][nt][rg] + (nt ? bv1 : bv0));
  }
  __syncthreads();

  // ---- LN: x = h + dh; out = (x-mu)*rstd*g + b ----
  {
    const int r = t >> 3;       // 0..127
    const int part = t & 7;     // 0..7
    const int c0 = part * 16;
    const float* hrow = h + hb + (size_t)r * HD + c0;
    float xs[16];
    float s1 = 0.f, s2 = 0.f;
#pragma unroll
    for (int q = 0; q < 4; ++q) {
      float4 hv = *(const float4*)(hrow + q * 4);
      short4 dv = *(const short4*)&sBs[r * PP + c0 + q * 4];
      float x0 = hv.x + b2f((unsigned short)dv.x);
      float x1 = hv.y + b2f((unsigned short)dv.y);
      float x2 = hv.z + b2f((unsigned short)dv.z);
      float x3 = hv.w + b2f((unsigned short)dv.w);
      xs[q * 4 + 0] = x0; xs[q * 4 + 1] = x1; xs[q * 4 + 2] = x2; xs[q * 4 + 3] = x3;
      s1 += x0 + x1 + x2 + x3;
      s2 += x0 * x0 + x1 * x1 + x2 * x2 + x3 * x3;
    }
    s1 += __shfl_xor(s1, 1); s2 += __shfl_xor(s2, 1);
    s1 += __shfl_xor(s1, 2); s2 += __shfl_xor(s2, 2);
    s1 += __shfl_xor(s1, 4); s2 += __shfl_xor(s2, 4);
    float mean = s1 * (1.0f / 128.0f);
    float var = s2 * (1.0f / 128.0f) - mean * mean;
    float rstd = rsqrtf(fmaxf(var, 0.f) + 1e-5f);
    float* orow = out + hb + (size_t)r * HD + c0;
#pragma unroll
    for (int q = 0; q < 4; ++q) {
      float4 gv = *(const float4*)(ln_g + c0 + q * 4);
      float4 bv = *(const float4*)(ln_b + c0 + q * 4);
      float4 ov;
      ov.x = (xs[q * 4 + 0] - mean) * rstd * gv.x + bv.x;
      ov.y = (xs[q * 4 + 1] - mean) * rstd * gv.y + bv.y;
      ov.z = (xs[q * 4 + 2] - mean) * rstd * gv.z + bv.z;
      ov.w = (xs[q * 4 + 3] - mean) * rstd * gv.w + bv.w;
      *(float4*)(orow + q * 4) = ov;
    }
  }
}

extern "C" void kernel_launch(void* const* d_in, const int* in_sizes, int n_in,
                              void* d_out, int out_size, void* d_ws, size_t ws_size,
                              hipStream_t stream) {
  const float* h      = (const float*)d_in[0];
  const float* coord  = (const float*)d_in[1];
  const float* msg_w1 = (const float*)d_in[2];
  const float* msg_b1 = (const float*)d_in[3];
  const float* msg_w2 = (const float*)d_in[4];
  const float* msg_b2 = (const float*)d_in[5];
  const float* upd_w1 = (const float*)d_in[6];
  const float* upd_b1 = (const float*)d_in[7];
  const float* upd_w2 = (const float*)d_in[8];
  const float* upd_b2 = (const float*)d_in[9];
  const float* ln_g   = (const float*)d_in[10];
  const float* ln_b   = (const float*)d_in[11];

  gno_mfma<<<NB * (NN / TILE), 1024, 0, stream>>>(
      h, coord, msg_w1, msg_b1, msg_w2, msg_b2, upd_w1, upd_b1, upd_w2, upd_b2,
      ln_g, ln_b, (float*)d_out);
}

// Round 14
// 353.098 us; speedup vs baseline: 2.5864x; 2.5864x over previous
//
// Round 14: 768-thread / 12-wave (3 waves/SIMD), TILE=128.
// 1024-thread WGs force a 128-reg/wave budget (16 waves co-resident; 512-reg
// file per SIMD slot, m69 law) -> our ~150-reg working set spills (r12/r13:
// VGPR 64, FETCH 810 MB). 12 waves -> 170-reg budget: fits. LDS 148.5 KB > 80 KB
// keeps the single-WG-per-CU guarantee (co-residency corruption law, r11).
// Per-element arithmetic identical to r11-r13 (absmax 0.03125).
#include <hip/hip_runtime.h>
#include <math.h>

#define NN    16384
#define NB    8
#define HD    128
#define TILE  128
#define HALO  6
#define NTHR  768
#define RWS   140     // TILE + 2*HALO (valid rows)
#define RWSP  144     // padded to 9 m-tiles of 16
#define PP    136     // bf16 pitch in shorts: 272 B/row, 16B-aligned

typedef short v8s __attribute__((ext_vector_type(8)));
typedef float v4f __attribute__((ext_vector_type(4)));

__device__ __forceinline__ unsigned short f2b(float x) {   // RNE, == v_cvt_bf16
  union { float f; unsigned u; } v; v.f = x;
  unsigned r = v.u + 0x7FFFu + ((v.u >> 16) & 1u);
  return (unsigned short)(r >> 16);
}
__device__ __forceinline__ float b2f(unsigned short u) {
  union { unsigned u; float f; } v; v.u = ((unsigned)u) << 16; return v.f;
}
// fast silu: v_exp_f32 + v_rcp_f32 (validated rounds 8/11)
__device__ __forceinline__ float silu_f(float z) {
  return z * __frcp_rn(1.0f + __expf(-z));
}
// 8 fp32 -> 8 bf16 via 4 hardware packed converts (RNE), union-punned
__device__ __forceinline__ v8s cvt8(const float* p) {
  union { v8s s; unsigned u[4]; } r;
#pragma unroll
  for (int q = 0; q < 4; ++q)
    asm("v_cvt_pk_bf16_f32 %0, %1, %2" : "=v"(r.u[q]) : "v"(p[2 * q]), "v"(p[2 * q + 1]));
  return r.s;
}

// MFMA GEMM, pure bf16: acc[mt][nt] += X[moff+mt*16+m][:] @ W[:][n]
// X: bf16 plane in LDS (pitch PP) -> 1x ds_read_b128 per fragment.
// W: fp32 in GLOBAL, row-major [128][128], cvt on the fly (4 cvt_pk/fragment).
template<int MT>
__device__ __forceinline__ void mgemm(const short* X, const float* __restrict__ W,
                                      int moff, int wn, int l15, int quad, v4f acc[][2]) {
  const int k0q = quad * 8;
  v8s wf[2][4];
#pragma unroll
  for (int nt = 0; nt < 2; ++nt) {
    const int n = wn * 32 + nt * 16 + l15;
#pragma unroll
    for (int ks = 0; ks < 4; ++ks) {
      float wv[8];
#pragma unroll
      for (int j = 0; j < 8; ++j) wv[j] = W[(ks * 32 + k0q + j) * HD + n];
      wf[nt][ks] = cvt8(wv);
    }
  }
#pragma unroll
  for (int ks = 0; ks < 4; ++ks) {
#pragma unroll
    for (int mt = 0; mt < MT; ++mt) {
      const int xo = (moff + mt * 16 + l15) * PP + ks * 32 + k0q;
      v8s a = *(const v8s*)&X[xo];
#pragma unroll
      for (int nt = 0; nt < 2; ++nt)
        acc[mt][nt] = __builtin_amdgcn_mfma_f32_16x16x32_bf16(a, wf[nt][ks], acc[mt][nt], 0, 0, 0);
    }
  }
}

// run a 3-or-2 m-tile GEMM slice and store bf16 results via functor-free inline
#define GEMM_SLICE(MTILES, XPLANE, WPTR, MOFF, DST, BIAS0, BIAS1)                  \
  {                                                                                \
    v4f acc[MTILES][2];                                                            \
    _Pragma("unroll") for (int mt = 0; mt < MTILES; ++mt)                          \
        _Pragma("unroll") for (int nt = 0; nt < 2; ++nt)                           \
            acc[mt][nt] = (v4f){0.f, 0.f, 0.f, 0.f};                               \
    mgemm<MTILES>(XPLANE, WPTR, MOFF, wn, l15, quad, acc);                         \
    _Pragma("unroll") for (int mt = 0; mt < MTILES; ++mt)                          \
        _Pragma("unroll") for (int nt = 0; nt < 2; ++nt)                           \
            _Pragma("unroll") for (int rg = 0; rg < 4; ++rg)                       \
                DST[(dbase + mt * 16 + quad * 4 + rg) * PP + wn * 32 + nt * 16 +   \
                    l15] = (short)f2b(acc[mt][nt][rg] + (nt ? BIAS1 : BIAS0));     \
  }

__global__ __launch_bounds__(NTHR, 1) void gno_mfma(
    const float* __restrict__ h, const float* __restrict__ coord,
    const float* __restrict__ msg_w1, const float* __restrict__ msg_b1,
    const float* __restrict__ msg_w2, const float* __restrict__ msg_b2,
    const float* __restrict__ upd_w1, const float* __restrict__ upd_b1,
    const float* __restrict__ upd_w2, const float* __restrict__ upd_b2,
    const float* __restrict__ ln_g, const float* __restrict__ ln_b,
    float* __restrict__ out) {
  // LDS = 39168 + 39168 + 34816 + 34816 + 576 = 148544 B -> 1 WG/CU, 12 waves
  __shared__ short sHs[RWSP * PP];   // h bf16 (G1,G2,G4)
  __shared__ short sBs[RWSP * PP];   // B bf16 (G1->MSG), then dh bf16 (G5->LN)
  __shared__ short sP1[TILE * PP];   // A (G2->MSG), then agg (G3->G4)
  __shared__ short sP2[TILE * PP];   // s (MSG->G3), then t (G4->G5)
  __shared__ float sC[RWSP];         // coord

  const int t = threadIdx.x;
  const int wave = t >> 6, lane = t & 63, l15 = lane & 15, quad = lane >> 4;
  const int wn = wave & 3;            // column group: cols [wn*32, wn*32+32)
  const int wm = wave >> 2;           // row group 0..2
  const int b = blockIdx.x / (NN / TILE);
  const int n0 = (blockIdx.x % (NN / TILE)) * TILE;
  const size_t hb = ((size_t)b * NN + n0) * HD;
  const int col0 = wn * 32 + l15, col1 = col0 + 16;

  // ---- defensive zero-init of ALL LDS (barrier-fenced from staging) ----
  for (int e = t; e < RWSP * PP / 2; e += NTHR) {
    ((int*)sHs)[e] = 0; ((int*)sBs)[e] = 0;
  }
  for (int e = t; e < TILE * PP / 2; e += NTHR) {
    ((int*)sP1)[e] = 0; ((int*)sP2)[e] = 0;
  }
  __syncthreads();

  // ---- stage h -> bf16 plane (hardware cvt_pk); zero-fill OOB rows ----
  for (int e = t; e < RWSP * HD / 4; e += NTHR) {  // 4608 quads
    const int r = e >> 5, c4 = (e & 31) << 2;
    const int g = n0 - HALO + r;
    float4 v = {0.f, 0.f, 0.f, 0.f};
    if (g >= 0 && g < NN) v = *(const float4*)&h[((size_t)b * NN + g) * HD + c4];
    unsigned h01, h23;
    asm("v_cvt_pk_bf16_f32 %0, %1, %2" : "=v"(h01) : "v"(v.x), "v"(v.y));
    asm("v_cvt_pk_bf16_f32 %0, %1, %2" : "=v"(h23) : "v"(v.z), "v"(v.w));
    *(uint2*)&sHs[r * PP + c4] = make_uint2(h01, h23);
  }
  if (t < RWSP) {
    const int g = n0 - HALO + t;
    sC[t] = (g >= 0 && g < NN) ? coord[(size_t)b * NN + g] : 0.f;
  }
  __syncthreads();

  // ---- G1 (MFMA): B = sH(144 rows) @ msg_w1[128:256] -> sBs bf16 ----
  // 9 m-tiles split 3+3+3 across the 3 row-groups.
  {
    const int dbase = wm * 48;
    GEMM_SLICE(3, sHs, msg_w1 + 128 * HD, wm * 48, sBs, 0.f, 0.f);
  }
  // ---- G2 (MFMA): A = sH(tile rows) @ msg_w1[0:128] + b1 -> sP1 bf16 ----
  // 8 m-tiles split 3+3+2.
  {
    const float bv0 = msg_b1[col0], bv1 = msg_b1[col1];
    const int dbase = wm * 48;
    if (wm < 2) {
      GEMM_SLICE(3, sHs, msg_w1, HALO + wm * 48, sP1, bv0, bv1);
    } else {
      GEMM_SLICE(2, sHs, msg_w1, HALO + 96, sP1, bv0, bv1);
    }
  }
  __syncthreads();

  // ---- MSG: s_i = (1/cnt) * sum silu(A_i + B_j + dc*w1_last) -> sP2 bf16 ----
  {
    const int c = t & 127;
    const int grp = t >> 7;   // 0..5; rows strided by 6
    const float wl = msg_w1[256 * HD + c];
    for (int r = grp; r < TILE; r += 6) {
      const int i = n0 + r;
      const float a = b2f((unsigned short)sP1[r * PP + c]);
      const float ci = sC[r + HALO];
      float s = 0.f;
#pragma unroll
      for (int d = -HALO; d <= HALO; ++d) {
        if (d == 0) continue;
        const int j = i + d;
        if (j >= 0 && j < NN) {
          const int rj = r + HALO + d;
          const float z = a + b2f((unsigned short)sBs[rj * PP + c]) + (sC[rj] - ci) * wl;
          s += silu_f(z);
        }
      }
      const int cnt = min(i, HALO) + min(NN - 1 - i, HALO);
      sP2[r * PP + c] = (short)f2b(s / (float)cnt);
    }
  }
  __syncthreads();

  // ---- G3 (MFMA): agg = P2(s) @ msg_w2 + b2 -> sP1 (A dead); 3+3+2 ----
  {
    const float bv0 = msg_b2[col0], bv1 = msg_b2[col1];
    const int dbase = wm * 48;
    if (wm < 2) {
      GEMM_SLICE(3, sP2, msg_w2, wm * 48, sP1, bv0, bv1);
    } else {
      GEMM_SLICE(2, sP2, msg_w2, 96, sP1, bv0, bv1);
    }
  }
  __syncthreads();

  // ---- G4 (MFMA): t = silu(sH@upd_w1[0:128] + P1(agg)@upd_w1[128:256] + ub1) -> sP2 ----
  {
    const float bv0 = upd_b1[col0], bv1 = upd_b1[col1];
    if (wm < 2) {
      v4f acc[3][2];
#pragma unroll
      for (int mt = 0; mt < 3; ++mt)
#pragma unroll
        for (int nt = 0; nt < 2; ++nt) acc[mt][nt] = (v4f){0.f, 0.f, 0.f, 0.f};
      mgemm<3>(sHs, upd_w1, HALO + wm * 48, wn, l15, quad, acc);
      mgemm<3>(sP1, upd_w1 + 128 * HD, wm * 48, wn, l15, quad, acc);
#pragma unroll
      for (int mt = 0; mt < 3; ++mt)
#pragma unroll
        for (int nt = 0; nt < 2; ++nt)
#pragma unroll
          for (int rg = 0; rg < 4; ++rg)
            sP2[(wm * 48 + mt * 16 + quad * 4 + rg) * PP + wn * 32 + nt * 16 + l15] =
                (short)f2b(silu_f(acc[mt][nt][rg] + (nt ? bv1 : bv0)));
    } else {
      v4f acc[2][2];
#pragma unroll
      for (int mt = 0; mt < 2; ++mt)
#pragma unroll
        for (int nt = 0; nt < 2; ++nt) acc[mt][nt] = (v4f){0.f, 0.f, 0.f, 0.f};
      mgemm<2>(sHs, upd_w1, HALO + 96, wn, l15, quad, acc);
      mgemm<2>(sP1, upd_w1 + 128 * HD, 96, wn, l15, quad, acc);
#pragma unroll
      for (int mt = 0; mt < 2; ++mt)
#pragma unroll
        for (int nt = 0; nt < 2; ++nt)
#pragma unroll
          for (int rg = 0; rg < 4; ++rg)
            sP2[(96 + mt * 16 + quad * 4 + rg) * PP + wn * 32 + nt * 16 + l15] =
                (short)f2b(silu_f(acc[mt][nt][rg] + (nt ? bv1 : bv0)));
    }
  }
  __syncthreads();

  // ---- G5 (MFMA): dh = P2(t) @ upd_w2 + ub2 -> sBs bf16 rows 0..127; 3+3+2 ----
  {
    const float bv0 = upd_b2[col0], bv1 = upd_b2[col1];
    const int dbase = wm * 48;
    if (wm < 2) {
      GEMM_SLICE(3, sP2, upd_w2, wm * 48, sBs, bv0, bv1);
    } else {
      GEMM_SLICE(2, sP2, upd_w2, 96, sBs, bv0, bv1);
    }
  }
  __syncthreads();

  // ---- LN: x = h + dh; out = (x-mu)*rstd*g + b (strided: 1024 items / 768 thr) ----
  for (int idx = t; idx < TILE * 8; idx += NTHR) {
    const int r = idx >> 3;     // 0..127
    const int part = idx & 7;   // 0..7
    const int c0 = part * 16;
    const float* hrow = h + hb + (size_t)r * HD + c0;
    float xs[16];
    float s1 = 0.f, s2 = 0.f;
#pragma unroll
    for (int q = 0; q < 4; ++q) {
      float4 hv = *(const float4*)(hrow + q * 4);
      short4 dv = *(const short4*)&sBs[r * PP + c0 + q * 4];
      float x0 = hv.x + b2f((unsigned short)dv.x);
      float x1 = hv.y + b2f((unsigned short)dv.y);
      float x2 = hv.z + b2f((unsigned short)dv.z);
      float x3 = hv.w + b2f((unsigned short)dv.w);
      xs[q * 4 + 0] = x0; xs[q * 4 + 1] = x1; xs[q * 4 + 2] = x2; xs[q * 4 + 3] = x3;
      s1 += x0 + x1 + x2 + x3;
      s2 += x0 * x0 + x1 * x1 + x2 * x2 + x3 * x3;
    }
    s1 += __shfl_xor(s1, 1); s2 += __shfl_xor(s2, 1);
    s1 += __shfl_xor(s1, 2); s2 += __shfl_xor(s2, 2);
    s1 += __shfl_xor(s1, 4); s2 += __shfl_xor(s2, 4);
    float mean = s1 * (1.0f / 128.0f);
    float var = s2 * (1.0f / 128.0f) - mean * mean;
    float rstd = rsqrtf(fmaxf(var, 0.f) + 1e-5f);
    float* orow = out + hb + (size_t)r * HD + c0;
#pragma unroll
    for (int q = 0; q < 4; ++q) {
      float4 gv = *(const float4*)(ln_g + c0 + q * 4);
      float4 bv = *(const float4*)(ln_b + c0 + q * 4);
      float4 ov;
      ov.x = (xs[q * 4 + 0] - mean) * rstd * gv.x + bv.x;
      ov.y = (xs[q * 4 + 1] - mean) * rstd * gv.y + bv.y;
      ov.z = (xs[q * 4 + 2] - mean) * rstd * gv.z + bv.z;
      ov.w = (xs[q * 4 + 3] - mean) * rstd * gv.w + bv.w;
      *(float4*)(orow + q * 4) = ov;
    }
  }
}

extern "C" void kernel_launch(void* const* d_in, const int* in_sizes, int n_in,
                              void* d_out, int out_size, void* d_ws, size_t ws_size,
                              hipStream_t stream) {
  const float* h      = (const float*)d_in[0];
  const float* coord  = (const float*)d_in[1];
  const float* msg_w1 = (const float*)d_in[2];
  const float* msg_b1 = (const float*)d_in[3];
  const float* msg_w2 = (const float*)d_in[4];
  const float* msg_b2 = (const float*)d_in[5];
  const float* upd_w1 = (const float*)d_in[6];
  const float* upd_b1 = (const float*)d_in[7];
  const float* upd_w2 = (const float*)d_in[8];
  const float* upd_b2 = (const float*)d_in[9];
  const float* ln_g   = (const float*)d_in[10];
  const float* ln_b   = (const float*)d_in[11];

  gno_mfma<<<NB * (NN / TILE), NTHR, 0, stream>>>(
      h, coord, msg_w1, msg_b1, msg_w2, msg_b2, upd_w1, upd_b1, upd_w2, upd_b2,
      ln_g, ln_b, (float*)d_out);
}

// Round 15
// 331.535 us; speedup vs baseline: 2.7546x; 1.0650x over previous
//
// Round 15: r14 structure (768t/12w, TILE=128, pure bf16, 148.5 KB LDS = 1 WG/CU)
// with three VALU cuts:
//  1) MSG interior fast path (no per-neighbor bounds check, cnt=12 const)
//  2) GEMM stores via v_cvt_pk_bf16_f32 pairs (1 cvt + 1 shift per 2 values)
//  3) defensive LDS zero-init removed (all reads producer-covered; the init
//     never prevented the co-residency corruption anyway)
#include <hip/hip_runtime.h>
#include <math.h>

#define NN    16384
#define NB    8
#define HD    128
#define TILE  128
#define HALO  6
#define NTHR  768
#define RWS   140     // TILE + 2*HALO (valid rows)
#define RWSP  144     // padded to 9 m-tiles of 16
#define PP    136     // bf16 pitch in shorts: 272 B/row, 16B-aligned

typedef short v8s __attribute__((ext_vector_type(8)));
typedef float v4f __attribute__((ext_vector_type(4)));

__device__ __forceinline__ unsigned short f2b(float x) {   // RNE, == v_cvt_bf16
  union { float f; unsigned u; } v; v.f = x;
  unsigned r = v.u + 0x7FFFu + ((v.u >> 16) & 1u);
  return (unsigned short)(r >> 16);
}
__device__ __forceinline__ float b2f(unsigned short u) {
  union { unsigned u; float f; } v; v.u = ((unsigned)u) << 16; return v.f;
}
// fast silu: v_exp_f32 + v_rcp_f32 (validated rounds 8/11/14)
__device__ __forceinline__ float silu_f(float z) {
  return z * __frcp_rn(1.0f + __expf(-z));
}
// 8 fp32 -> 8 bf16 via 4 hardware packed converts (RNE), union-punned
__device__ __forceinline__ v8s cvt8(const float* p) {
  union { v8s s; unsigned u[4]; } r;
#pragma unroll
  for (int q = 0; q < 4; ++q)
    asm("v_cvt_pk_bf16_f32 %0, %1, %2" : "=v"(r.u[q]) : "v"(p[2 * q]), "v"(p[2 * q + 1]));
  return r.s;
}
// store 2 fp32 as bf16 to two (row-strided) LDS slots: 1 cvt_pk + 1 shift
__device__ __forceinline__ void st2(short* dst, int i0, int i1, float a, float b) {
  unsigned pk;
  asm("v_cvt_pk_bf16_f32 %0, %1, %2" : "=v"(pk) : "v"(a), "v"(b));
  dst[i0] = (short)pk;
  dst[i1] = (short)(pk >> 16);
}

// MFMA GEMM, pure bf16: acc[mt][nt] += X[moff+mt*16+m][:] @ W[:][n]
// X: bf16 plane in LDS (pitch PP) -> 1x ds_read_b128 per fragment.
// W: fp32 in GLOBAL, row-major [128][128], cvt on the fly (4 cvt_pk/fragment).
template<int MT>
__device__ __forceinline__ void mgemm(const short* X, const float* __restrict__ W,
                                      int moff, int wn, int l15, int quad, v4f acc[][2]) {
  const int k0q = quad * 8;
  v8s wf[2][4];
#pragma unroll
  for (int nt = 0; nt < 2; ++nt) {
    const int n = wn * 32 + nt * 16 + l15;
#pragma unroll
    for (int ks = 0; ks < 4; ++ks) {
      float wv[8];
#pragma unroll
      for (int j = 0; j < 8; ++j) wv[j] = W[(ks * 32 + k0q + j) * HD + n];
      wf[nt][ks] = cvt8(wv);
    }
  }
#pragma unroll
  for (int ks = 0; ks < 4; ++ks) {
#pragma unroll
    for (int mt = 0; mt < MT; ++mt) {
      const int xo = (moff + mt * 16 + l15) * PP + ks * 32 + k0q;
      v8s a = *(const v8s*)&X[xo];
#pragma unroll
      for (int nt = 0; nt < 2; ++nt)
        acc[mt][nt] = __builtin_amdgcn_mfma_f32_16x16x32_bf16(a, wf[nt][ks], acc[mt][nt], 0, 0, 0);
    }
  }
}

// GEMM slice + paired bf16 store (1 cvt_pk + 1 shift per 2 values)
#define GEMM_SLICE(MTILES, XPLANE, WPTR, MOFF, DST, BIAS0, BIAS1)                  \
  {                                                                                \
    v4f acc[MTILES][2];                                                            \
    _Pragma("unroll") for (int mt = 0; mt < MTILES; ++mt)                          \
        _Pragma("unroll") for (int nt = 0; nt < 2; ++nt)                           \
            acc[mt][nt] = (v4f){0.f, 0.f, 0.f, 0.f};                               \
    mgemm<MTILES>(XPLANE, WPTR, MOFF, wn, l15, quad, acc);                         \
    _Pragma("unroll") for (int mt = 0; mt < MTILES; ++mt)                          \
        _Pragma("unroll") for (int nt = 0; nt < 2; ++nt) {                         \
          const float bb = nt ? BIAS1 : BIAS0;                                     \
          const int rb = (dbase + mt * 16 + quad * 4) * PP + wn * 32 + nt * 16 + l15; \
          st2(DST, rb, rb + PP, acc[mt][nt][0] + bb, acc[mt][nt][1] + bb);         \
          st2(DST, rb + 2 * PP, rb + 3 * PP, acc[mt][nt][2] + bb, acc[mt][nt][3] + bb); \
        }                                                                          \
  }

__global__ __launch_bounds__(NTHR, 1) void gno_mfma(
    const float* __restrict__ h, const float* __restrict__ coord,
    const float* __restrict__ msg_w1, const float* __restrict__ msg_b1,
    const float* __restrict__ msg_w2, const float* __restrict__ msg_b2,
    const float* __restrict__ upd_w1, const float* __restrict__ upd_b1,
    const float* __restrict__ upd_w2, const float* __restrict__ upd_b2,
    const float* __restrict__ ln_g, const float* __restrict__ ln_b,
    float* __restrict__ out) {
  // LDS = 39168 + 39168 + 34816 + 34816 + 576 = 148544 B -> 1 WG/CU, 12 waves
  __shared__ short sHs[RWSP * PP];   // h bf16 (G1,G2,G4)
  __shared__ short sBs[RWSP * PP];   // B bf16 (G1->MSG), then dh bf16 (G5->LN)
  __shared__ short sP1[TILE * PP];   // A (G2->MSG), then agg (G3->G4)
  __shared__ short sP2[TILE * PP];   // s (MSG->G3), then t (G4->G5)
  __shared__ float sC[RWSP];         // coord

  const int t = threadIdx.x;
  const int wave = t >> 6, lane = t & 63, l15 = lane & 15, quad = lane >> 4;
  const int wn = wave & 3;            // column group: cols [wn*32, wn*32+32)
  const int wm = wave >> 2;           // row group 0..2
  const int b = blockIdx.x / (NN / TILE);
  const int n0 = (blockIdx.x % (NN / TILE)) * TILE;
  const size_t hb = ((size_t)b * NN + n0) * HD;
  const int col0 = wn * 32 + l15, col1 = col0 + 16;

  // ---- stage h -> bf16 plane (hardware cvt_pk); zero-fill OOB rows ----
  for (int e = t; e < RWSP * HD / 4; e += NTHR) {  // 4608 quads
    const int r = e >> 5, c4 = (e & 31) << 2;
    const int g = n0 - HALO + r;
    float4 v = {0.f, 0.f, 0.f, 0.f};
    if (g >= 0 && g < NN) v = *(const float4*)&h[((size_t)b * NN + g) * HD + c4];
    unsigned h01, h23;
    asm("v_cvt_pk_bf16_f32 %0, %1, %2" : "=v"(h01) : "v"(v.x), "v"(v.y));
    asm("v_cvt_pk_bf16_f32 %0, %1, %2" : "=v"(h23) : "v"(v.z), "v"(v.w));
    *(uint2*)&sHs[r * PP + c4] = make_uint2(h01, h23);
  }
  if (t < RWSP) {
    const int g = n0 - HALO + t;
    sC[t] = (g >= 0 && g < NN) ? coord[(size_t)b * NN + g] : 0.f;
  }
  __syncthreads();

  // ---- G1 (MFMA): B = sH(144 rows) @ msg_w1[128:256] -> sBs bf16; 3+3+3 ----
  {
    const int dbase = wm * 48;
    GEMM_SLICE(3, sHs, msg_w1 + 128 * HD, wm * 48, sBs, 0.f, 0.f);
  }
  // ---- G2 (MFMA): A = sH(tile rows) @ msg_w1[0:128] + b1 -> sP1 bf16; 3+3+2 ----
  {
    const float bv0 = msg_b1[col0], bv1 = msg_b1[col1];
    const int dbase = wm * 48;
    if (wm < 2) {
      GEMM_SLICE(3, sHs, msg_w1, HALO + wm * 48, sP1, bv0, bv1);
    } else {
      GEMM_SLICE(2, sHs, msg_w1, HALO + 96, sP1, bv0, bv1);
    }
  }
  __syncthreads();

  // ---- MSG: s_i = (1/cnt) * sum silu(A_i + B_j + dc*w1_last) -> sP2 bf16 ----
  {
    const int c = t & 127;
    const int grp = t >> 7;   // 0..5; rows strided by 6
    const float wl = msg_w1[256 * HD + c];
    const bool interior = (n0 >= HALO) && (n0 + TILE + HALO <= NN);
    if (interior) {           // 126/128 block positions: no bounds checks, cnt=12
      for (int r = grp; r < TILE; r += 6) {
        const float a = b2f((unsigned short)sP1[r * PP + c]);
        const float ci = sC[r + HALO];
        float s = 0.f;
#pragma unroll
        for (int d = -HALO; d <= HALO; ++d) {
          if (d == 0) continue;
          const int rj = r + HALO + d;
          s += silu_f(a + b2f((unsigned short)sBs[rj * PP + c]) + (sC[rj] - ci) * wl);
        }
        sP2[r * PP + c] = (short)f2b(s * (1.0f / 12.0f));
      }
    } else {
      for (int r = grp; r < TILE; r += 6) {
        const int i = n0 + r;
        const float a = b2f((unsigned short)sP1[r * PP + c]);
        const float ci = sC[r + HALO];
        float s = 0.f;
#pragma unroll
        for (int d = -HALO; d <= HALO; ++d) {
          if (d == 0) continue;
          const int j = i + d;
          if (j >= 0 && j < NN) {
            const int rj = r + HALO + d;
            s += silu_f(a + b2f((unsigned short)sBs[rj * PP + c]) + (sC[rj] - ci) * wl);
          }
        }
        const int cnt = min(i, HALO) + min(NN - 1 - i, HALO);
        sP2[r * PP + c] = (short)f2b(s / (float)cnt);
      }
    }
  }
  __syncthreads();

  // ---- G3 (MFMA): agg = P2(s) @ msg_w2 + b2 -> sP1 (A dead); 3+3+2 ----
  {
    const float bv0 = msg_b2[col0], bv1 = msg_b2[col1];
    const int dbase = wm * 48;
    if (wm < 2) {
      GEMM_SLICE(3, sP2, msg_w2, wm * 48, sP1, bv0, bv1);
    } else {
      GEMM_SLICE(2, sP2, msg_w2, 96, sP1, bv0, bv1);
    }
  }
  __syncthreads();

  // ---- G4 (MFMA): t = silu(sH@upd_w1[0:128] + P1(agg)@upd_w1[128:256] + ub1) -> sP2 ----
  {
    const float bv0 = upd_b1[col0], bv1 = upd_b1[col1];
    if (wm < 2) {
      v4f acc[3][2];
#pragma unroll
      for (int mt = 0; mt < 3; ++mt)
#pragma unroll
        for (int nt = 0; nt < 2; ++nt) acc[mt][nt] = (v4f){0.f, 0.f, 0.f, 0.f};
      mgemm<3>(sHs, upd_w1, HALO + wm * 48, wn, l15, quad, acc);
      mgemm<3>(sP1, upd_w1 + 128 * HD, wm * 48, wn, l15, quad, acc);
#pragma unroll
      for (int mt = 0; mt < 3; ++mt)
#pragma unroll
        for (int nt = 0; nt < 2; ++nt) {
          const float bb = nt ? bv1 : bv0;
          const int rb = (wm * 48 + mt * 16 + quad * 4) * PP + wn * 32 + nt * 16 + l15;
          st2(sP2, rb, rb + PP, silu_f(acc[mt][nt][0] + bb), silu_f(acc[mt][nt][1] + bb));
          st2(sP2, rb + 2 * PP, rb + 3 * PP, silu_f(acc[mt][nt][2] + bb), silu_f(acc[mt][nt][3] + bb));
        }
    } else {
      v4f acc[2][2];
#pragma unroll
      for (int mt = 0; mt < 2; ++mt)
#pragma unroll
        for (int nt = 0; nt < 2; ++nt) acc[mt][nt] = (v4f){0.f, 0.f, 0.f, 0.f};
      mgemm<2>(sHs, upd_w1, HALO + 96, wn, l15, quad, acc);
      mgemm<2>(sP1, upd_w1 + 128 * HD, 96, wn, l15, quad, acc);
#pragma unroll
      for (int mt = 0; mt < 2; ++mt)
#pragma unroll
        for (int nt = 0; nt < 2; ++nt) {
          const float bb = nt ? bv1 : bv0;
          const int rb = (96 + mt * 16 + quad * 4) * PP + wn * 32 + nt * 16 + l15;
          st2(sP2, rb, rb + PP, silu_f(acc[mt][nt][0] + bb), silu_f(acc[mt][nt][1] + bb));
          st2(sP2, rb + 2 * PP, rb + 3 * PP, silu_f(acc[mt][nt][2] + bb), silu_f(acc[mt][nt][3] + bb));
        }
    }
  }
  __syncthreads();

  // ---- G5 (MFMA): dh = P2(t) @ upd_w2 + ub2 -> sBs bf16 rows 0..127; 3+3+2 ----
  {
    const float bv0 = upd_b2[col0], bv1 = upd_b2[col1];
    const int dbase = wm * 48;
    if (wm < 2) {
      GEMM_SLICE(3, sP2, upd_w2, wm * 48, sBs, bv0, bv1);
    } else {
      GEMM_SLICE(2, sP2, upd_w2, 96, sBs, bv0, bv1);
    }
  }
  __syncthreads();

  // ---- LN: x = h + dh; out = (x-mu)*rstd*g + b (strided: 1024 items / 768 thr) ----
  for (int idx = t; idx < TILE * 8; idx += NTHR) {
    const int r = idx >> 3;     // 0..127
    const int part = idx & 7;   // 0..7
    const int c0 = part * 16;
    const float* hrow = h + hb + (size_t)r * HD + c0;
    float xs[16];
    float s1 = 0.f, s2 = 0.f;
#pragma unroll
    for (int q = 0; q < 4; ++q) {
      float4 hv = *(const float4*)(hrow + q * 4);
      short4 dv = *(const short4*)&sBs[r * PP + c0 + q * 4];
      float x0 = hv.x + b2f((unsigned short)dv.x);
      float x1 = hv.y + b2f((unsigned short)dv.y);
      float x2 = hv.z + b2f((unsigned short)dv.z);
      float x3 = hv.w + b2f((unsigned short)dv.w);
      xs[q * 4 + 0] = x0; xs[q * 4 + 1] = x1; xs[q * 4 + 2] = x2; xs[q * 4 + 3] = x3;
      s1 += x0 + x1 + x2 + x3;
      s2 += x0 * x0 + x1 * x1 + x2 * x2 + x3 * x3;
    }
    s1 += __shfl_xor(s1, 1); s2 += __shfl_xor(s2, 1);
    s1 += __shfl_xor(s1, 2); s2 += __shfl_xor(s2, 2);
    s1 += __shfl_xor(s1, 4); s2 += __shfl_xor(s2, 4);
    float mean = s1 * (1.0f / 128.0f);
    float var = s2 * (1.0f / 128.0f) - mean * mean;
    float rstd = rsqrtf(fmaxf(var, 0.f) + 1e-5f);
    float* orow = out + hb + (size_t)r * HD + c0;
#pragma unroll
    for (int q = 0; q < 4; ++q) {
      float4 gv = *(const float4*)(ln_g + c0 + q * 4);
      float4 bv = *(const float4*)(ln_b + c0 + q * 4);
      float4 ov;
      ov.x = (xs[q * 4 + 0] - mean) * rstd * gv.x + bv.x;
      ov.y = (xs[q * 4 + 1] - mean) * rstd * gv.y + bv.y;
      ov.z = (xs[q * 4 + 2] - mean) * rstd * gv.z + bv.z;
      ov.w = (xs[q * 4 + 3] - mean) * rstd * gv.w + bv.w;
      *(float4*)(orow + q * 4) = ov;
    }
  }
}

extern "C" void kernel_launch(void* const* d_in, const int* in_sizes, int n_in,
                              void* d_out, int out_size, void* d_ws, size_t ws_size,
                              hipStream_t stream) {
  const float* h      = (const float*)d_in[0];
  const float* coord  = (const float*)d_in[1];
  const float* msg_w1 = (const float*)d_in[2];
  const float* msg_b1 = (const float*)d_in[3];
  const float* msg_w2 = (const float*)d_in[4];
  const float* msg_b2 = (const float*)d_in[5];
  const float* upd_w1 = (const float*)d_in[6];
  const float* upd_b1 = (const float*)d_in[7];
  const float* upd_w2 = (const float*)d_in[8];
  const float* upd_b2 = (const float*)d_in[9];
  const float* ln_g   = (const float*)d_in[10];
  const float* ln_b   = (const float*)d_in[11];

  gno_mfma<<<NB * (NN / TILE), NTHR, 0, stream>>>(
      h, coord, msg_w1, msg_b1, msg_w2, msg_b2, upd_w1, upd_b1, upd_w2, upd_b2,
      ln_g, ln_b, (float*)d_out);
}

// Round 16
// 316.522 us; speedup vs baseline: 2.8853x; 1.0474x over previous
//
// Round 16: r15 + weight prepack. Six 128x128 weight blocks packed ONCE to bf16
// octets in a device-global (192 KiB): fragment = 1x 16B coalesced load, zero
// per-use conversion (was 64 scalar fp32 loads + 32 cvt per mgemm, x6 per
// thread, x12 waves, x1024 blocks). f2b is RNE == cvt_pk: MFMA operand bits
// unchanged vs r15 (absmax 0.03125). Rounds 1-2 prepack failures are fully
// explained by the co-residency law (<=80KB LDS, 2 WG/CU); this kernel's
// 148.5 KB LDS guarantees 1 WG/CU.
#include <hip/hip_runtime.h>
#include <math.h>

#define NN    16384
#define NB    8
#define HD    128
#define TILE  128
#define HALO  6
#define NTHR  768
#define RWS   140     // TILE + 2*HALO (valid rows)
#define RWSP  144     // padded to 9 m-tiles of 16
#define PP    136     // bf16 pitch in shorts: 272 B/row, 16B-aligned

typedef short v8s __attribute__((ext_vector_type(8)));
typedef float v4f __attribute__((ext_vector_type(4)));

// prepacked bf16 weights: 6 x 128x128, octet layout ((k>>3)*128+n)*8+(k&7)
__device__ short g_wp[6 * 16384];

__device__ __forceinline__ unsigned short f2b(float x) {   // RNE, == v_cvt_bf16
  union { float f; unsigned u; } v; v.f = x;
  unsigned r = v.u + 0x7FFFu + ((v.u >> 16) & 1u);
  return (unsigned short)(r >> 16);
}
__device__ __forceinline__ float b2f(unsigned short u) {
  union { unsigned u; float f; } v; v.u = ((unsigned)u) << 16; return v.f;
}
// fast silu: v_exp_f32 + v_rcp_f32 (validated rounds 8/11/14/15)
__device__ __forceinline__ float silu_f(float z) {
  return z * __frcp_rn(1.0f + __expf(-z));
}
// store 2 fp32 as bf16 to two (row-strided) LDS slots: 1 cvt_pk + 1 shift
__device__ __forceinline__ void st2(short* dst, int i0, int i1, float a, float b) {
  unsigned pk;
  asm("v_cvt_pk_bf16_f32 %0, %1, %2" : "=v"(pk) : "v"(a), "v"(b));
  dst[i0] = (short)pk;
  dst[i1] = (short)(pk >> 16);
}

// prologue: pack the six weight blocks to bf16 octets (RNE, == cvt_pk bits)
__global__ void prepack_w(const float* __restrict__ msg_w1, const float* __restrict__ msg_w2,
                          const float* __restrict__ upd_w1, const float* __restrict__ upd_w2) {
  const int tt = blockIdx.x * 256 + threadIdx.x;   // 6*16384 threads
  const int m = tt >> 14, e = tt & 16383;
  const int k = e >> 7, n = e & 127;
  const float* src;
  switch (m) {
    case 0: src = msg_w1; break;             // A-part of msg_w1 (rows 0..127)
    case 1: src = msg_w1 + 128 * HD; break;  // B-part of msg_w1 (rows 128..255)
    case 2: src = msg_w2; break;
    case 3: src = upd_w1; break;             // h-part
    case 4: src = upd_w1 + 128 * HD; break;  // agg-part
    default: src = upd_w2; break;
  }
  g_wp[m * 16384 + (((k >> 3) * 128 + n) << 3) + (k & 7)] = (short)f2b(src[k * HD + n]);
}

// MFMA GEMM, pure bf16: acc[mt][nt] += X[moff+mt*16+m][:] @ W[:][n]
// X: bf16 plane in LDS (pitch PP) -> 1x ds_read_b128 per fragment.
// W: prepacked bf16 octets in global -> 1x 16B coalesced load per fragment.
template<int MT>
__device__ __forceinline__ void mgemm(const short* X, const short* __restrict__ Wp,
                                      int moff, int wn, int l15, int quad, v4f acc[][2]) {
  v8s wf[2][4];
#pragma unroll
  for (int nt = 0; nt < 2; ++nt) {
    const int n = wn * 32 + nt * 16 + l15;
#pragma unroll
    for (int ks = 0; ks < 4; ++ks)
      wf[nt][ks] = *(const v8s*)&Wp[((((ks * 4 + quad) << 7) + n) << 3)];
  }
#pragma unroll
  for (int ks = 0; ks < 4; ++ks) {
#pragma unroll
    for (int mt = 0; mt < MT; ++mt) {
      const int xo = (moff + mt * 16 + l15) * PP + ks * 32 + quad * 8;
      v8s a = *(const v8s*)&X[xo];
#pragma unroll
      for (int nt = 0; nt < 2; ++nt)
        acc[mt][nt] = __builtin_amdgcn_mfma_f32_16x16x32_bf16(a, wf[nt][ks], acc[mt][nt], 0, 0, 0);
    }
  }
}

// GEMM slice + paired bf16 store (1 cvt_pk + 1 shift per 2 values)
#define GEMM_SLICE(MTILES, XPLANE, WPTR, MOFF, DST, BIAS0, BIAS1)                  \
  {                                                                                \
    v4f acc[MTILES][2];                                                            \
    _Pragma("unroll") for (int mt = 0; mt < MTILES; ++mt)                          \
        _Pragma("unroll") for (int nt = 0; nt < 2; ++nt)                           \
            acc[mt][nt] = (v4f){0.f, 0.f, 0.f, 0.f};                               \
    mgemm<MTILES>(XPLANE, WPTR, MOFF, wn, l15, quad, acc);                         \
    _Pragma("unroll") for (int mt = 0; mt < MTILES; ++mt)                          \
        _Pragma("unroll") for (int nt = 0; nt < 2; ++nt) {                         \
          const float bb = nt ? BIAS1 : BIAS0;                                     \
          const int rb = (dbase + mt * 16 + quad * 4) * PP + wn * 32 + nt * 16 + l15; \
          st2(DST, rb, rb + PP, acc[mt][nt][0] + bb, acc[mt][nt][1] + bb);         \
          st2(DST, rb + 2 * PP, rb + 3 * PP, acc[mt][nt][2] + bb, acc[mt][nt][3] + bb); \
        }                                                                          \
  }

__global__ __launch_bounds__(NTHR, 1) void gno_mfma(
    const float* __restrict__ h, const float* __restrict__ coord,
    const float* __restrict__ msg_w1, const float* __restrict__ msg_b1,
    const float* __restrict__ msg_b2,
    const float* __restrict__ upd_b1, const float* __restrict__ upd_b2,
    const float* __restrict__ ln_g, const float* __restrict__ ln_b,
    float* __restrict__ out) {
  // LDS = 39168 + 39168 + 34816 + 34816 + 576 = 148544 B -> 1 WG/CU, 12 waves
  __shared__ short sHs[RWSP * PP];   // h bf16 (G1,G2,G4)
  __shared__ short sBs[RWSP * PP];   // B bf16 (G1->MSG), then dh bf16 (G5->LN)
  __shared__ short sP1[TILE * PP];   // A (G2->MSG), then agg (G3->G4)
  __shared__ short sP2[TILE * PP];   // s (MSG->G3), then t (G4->G5)
  __shared__ float sC[RWSP];         // coord

  const int t = threadIdx.x;
  const int wave = t >> 6, lane = t & 63, l15 = lane & 15, quad = lane >> 4;
  const int wn = wave & 3;            // column group: cols [wn*32, wn*32+32)
  const int wm = wave >> 2;           // row group 0..2
  const int b = blockIdx.x / (NN / TILE);
  const int n0 = (blockIdx.x % (NN / TILE)) * TILE;
  const size_t hb = ((size_t)b * NN + n0) * HD;
  const int col0 = wn * 32 + l15, col1 = col0 + 16;

  // ---- stage h -> bf16 plane (hardware cvt_pk); zero-fill OOB rows ----
  for (int e = t; e < RWSP * HD / 4; e += NTHR) {  // 4608 quads
    const int r = e >> 5, c4 = (e & 31) << 2;
    const int g = n0 - HALO + r;
    float4 v = {0.f, 0.f, 0.f, 0.f};
    if (g >= 0 && g < NN) v = *(const float4*)&h[((size_t)b * NN + g) * HD + c4];
    unsigned h01, h23;
    asm("v_cvt_pk_bf16_f32 %0, %1, %2" : "=v"(h01) : "v"(v.x), "v"(v.y));
    asm("v_cvt_pk_bf16_f32 %0, %1, %2" : "=v"(h23) : "v"(v.z), "v"(v.w));
    *(uint2*)&sHs[r * PP + c4] = make_uint2(h01, h23);
  }
  if (t < RWSP) {
    const int g = n0 - HALO + t;
    sC[t] = (g >= 0 && g < NN) ? coord[(size_t)b * NN + g] : 0.f;
  }
  __syncthreads();

  // ---- G1 (MFMA): B = sH(144 rows) @ W[m1] -> sBs bf16; 3+3+3 ----
  {
    const int dbase = wm * 48;
    GEMM_SLICE(3, sHs, g_wp + 1 * 16384, wm * 48, sBs, 0.f, 0.f);
  }
  // ---- G2 (MFMA): A = sH(tile rows) @ W[m0] + b1 -> sP1 bf16; 3+3+2 ----
  {
    const float bv0 = msg_b1[col0], bv1 = msg_b1[col1];
    const int dbase = wm * 48;
    if (wm < 2) {
      GEMM_SLICE(3, sHs, g_wp, HALO + wm * 48, sP1, bv0, bv1);
    } else {
      GEMM_SLICE(2, sHs, g_wp, HALO + 96, sP1, bv0, bv1);
    }
  }
  __syncthreads();

  // ---- MSG: s_i = (1/cnt) * sum silu(A_i + B_j + dc*w1_last) -> sP2 bf16 ----
  {
    const int c = t & 127;
    const int grp = t >> 7;   // 0..5; rows strided by 6
    const float wl = msg_w1[256 * HD + c];
    const bool interior = (n0 >= HALO) && (n0 + TILE + HALO <= NN);
    if (interior) {           // 126/128 block positions: no bounds checks, cnt=12
      for (int r = grp; r < TILE; r += 6) {
        const float a = b2f((unsigned short)sP1[r * PP + c]);
        const float ci = sC[r + HALO];
        float s = 0.f;
#pragma unroll
        for (int d = -HALO; d <= HALO; ++d) {
          if (d == 0) continue;
          const int rj = r + HALO + d;
          s += silu_f(a + b2f((unsigned short)sBs[rj * PP + c]) + (sC[rj] - ci) * wl);
        }
        sP2[r * PP + c] = (short)f2b(s * (1.0f / 12.0f));
      }
    } else {
      for (int r = grp; r < TILE; r += 6) {
        const int i = n0 + r;
        const float a = b2f((unsigned short)sP1[r * PP + c]);
        const float ci = sC[r + HALO];
        float s = 0.f;
#pragma unroll
        for (int d = -HALO; d <= HALO; ++d) {
          if (d == 0) continue;
          const int j = i + d;
          if (j >= 0 && j < NN) {
            const int rj = r + HALO + d;
            s += silu_f(a + b2f((unsigned short)sBs[rj * PP + c]) + (sC[rj] - ci) * wl);
          }
        }
        const int cnt = min(i, HALO) + min(NN - 1 - i, HALO);
        sP2[r * PP + c] = (short)f2b(s / (float)cnt);
      }
    }
  }
  __syncthreads();

  // ---- G3 (MFMA): agg = P2(s) @ W[m2] + b2 -> sP1 (A dead); 3+3+2 ----
  {
    const float bv0 = msg_b2[col0], bv1 = msg_b2[col1];
    const int dbase = wm * 48;
    if (wm < 2) {
      GEMM_SLICE(3, sP2, g_wp + 2 * 16384, wm * 48, sP1, bv0, bv1);
    } else {
      GEMM_SLICE(2, sP2, g_wp + 2 * 16384, 96, sP1, bv0, bv1);
    }
  }
  __syncthreads();

  // ---- G4 (MFMA): t = silu(sH@W[m3] + P1(agg)@W[m4] + ub1) -> sP2 ----
  {
    const float bv0 = upd_b1[col0], bv1 = upd_b1[col1];
    if (wm < 2) {
      v4f acc[3][2];
#pragma unroll
      for (int mt = 0; mt < 3; ++mt)
#pragma unroll
        for (int nt = 0; nt < 2; ++nt) acc[mt][nt] = (v4f){0.f, 0.f, 0.f, 0.f};
      mgemm<3>(sHs, g_wp + 3 * 16384, HALO + wm * 48, wn, l15, quad, acc);
      mgemm<3>(sP1, g_wp + 4 * 16384, wm * 48, wn, l15, quad, acc);
#pragma unroll
      for (int mt = 0; mt < 3; ++mt)
#pragma unroll
        for (int nt = 0; nt < 2; ++nt) {
          const float bb = nt ? bv1 : bv0;
          const int rb = (wm * 48 + mt * 16 + quad * 4) * PP + wn * 32 + nt * 16 + l15;
          st2(sP2, rb, rb + PP, silu_f(acc[mt][nt][0] + bb), silu_f(acc[mt][nt][1] + bb));
          st2(sP2, rb + 2 * PP, rb + 3 * PP, silu_f(acc[mt][nt][2] + bb), silu_f(acc[mt][nt][3] + bb));
        }
    } else {
      v4f acc[2][2];
#pragma unroll
      for (int mt = 0; mt < 2; ++mt)
#pragma unroll
        for (int nt = 0; nt < 2; ++nt) acc[mt][nt] = (v4f){0.f, 0.f, 0.f, 0.f};
      mgemm<2>(sHs, g_wp + 3 * 16384, HALO + 96, wn, l15, quad, acc);
      mgemm<2>(sP1, g_wp + 4 * 16384, 96, wn, l15, quad, acc);
#pragma unroll
      for (int mt = 0; mt < 2; ++mt)
#pragma unroll
        for (int nt = 0; nt < 2; ++nt) {
          const float bb = nt ? bv1 : bv0;
          const int rb = (96 + mt * 16 + quad * 4) * PP + wn * 32 + nt * 16 + l15;
          st2(sP2, rb, rb + PP, silu_f(acc[mt][nt][0] + bb), silu_f(acc[mt][nt][1] + bb));
          st2(sP2, rb + 2 * PP, rb + 3 * PP, silu_f(acc[mt][nt][2] + bb), silu_f(acc[mt][nt][3] + bb));
        }
    }
  }
  __syncthreads();

  // ---- G5 (MFMA): dh = P2(t) @ W[m5] + ub2 -> sBs bf16 rows 0..127; 3+3+2 ----
  {
    const float bv0 = upd_b2[col0], bv1 = upd_b2[col1];
    const int dbase = wm * 48;
    if (wm < 2) {
      GEMM_SLICE(3, sP2, g_wp + 5 * 16384, wm * 48, sBs, bv0, bv1);
    } else {
      GEMM_SLICE(2, sP2, g_wp + 5 * 16384, 96, sBs, bv0, bv1);
    }
  }
  __syncthreads();

  // ---- LN: x = h + dh; out = (x-mu)*rstd*g + b (strided: 1024 items / 768 thr) ----
  for (int idx = t; idx < TILE * 8; idx += NTHR) {
    const int r = idx >> 3;     // 0..127
    const int part = idx & 7;   // 0..7
    const int c0 = part * 16;
    const float* hrow = h + hb + (size_t)r * HD + c0;
    float xs[16];
    float s1 = 0.f, s2 = 0.f;
#pragma unroll
    for (int q = 0; q < 4; ++q) {
      float4 hv = *(const float4*)(hrow + q * 4);
      short4 dv = *(const short4*)&sBs[r * PP + c0 + q * 4];
      float x0 = hv.x + b2f((unsigned short)dv.x);
      float x1 = hv.y + b2f((unsigned short)dv.y);
      float x2 = hv.z + b2f((unsigned short)dv.z);
      float x3 = hv.w + b2f((unsigned short)dv.w);
      xs[q * 4 + 0] = x0; xs[q * 4 + 1] = x1; xs[q * 4 + 2] = x2; xs[q * 4 + 3] = x3;
      s1 += x0 + x1 + x2 + x3;
      s2 += x0 * x0 + x1 * x1 + x2 * x2 + x3 * x3;
    }
    s1 += __shfl_xor(s1, 1); s2 += __shfl_xor(s2, 1);
    s1 += __shfl_xor(s1, 2); s2 += __shfl_xor(s2, 2);
    s1 += __shfl_xor(s1, 4); s2 += __shfl_xor(s2, 4);
    float mean = s1 * (1.0f / 128.0f);
    float var = s2 * (1.0f / 128.0f) - mean * mean;
    float rstd = rsqrtf(fmaxf(var, 0.f) + 1e-5f);
    float* orow = out + hb + (size_t)r * HD + c0;
#pragma unroll
    for (int q = 0; q < 4; ++q) {
      float4 gv = *(const float4*)(ln_g + c0 + q * 4);
      float4 bv = *(const float4*)(ln_b + c0 + q * 4);
      float4 ov;
      ov.x = (xs[q * 4 + 0] - mean) * rstd * gv.x + bv.x;
      ov.y = (xs[q * 4 + 1] - mean) * rstd * gv.y + bv.y;
      ov.z = (xs[q * 4 + 2] - mean) * rstd * gv.z + bv.z;
      ov.w = (xs[q * 4 + 3] - mean) * rstd * gv.w + bv.w;
      *(float4*)(orow + q * 4) = ov;
    }
  }
}

extern "C" void kernel_launch(void* const* d_in, const int* in_sizes, int n_in,
                              void* d_out, int out_size, void* d_ws, size_t ws_size,
                              hipStream_t stream) {
  const float* h      = (const float*)d_in[0];
  const float* coord  = (const float*)d_in[1];
  const float* msg_w1 = (const float*)d_in[2];
  const float* msg_b1 = (const float*)d_in[3];
  const float* msg_w2 = (const float*)d_in[4];
  const float* msg_b2 = (const float*)d_in[5];
  const float* upd_w1 = (const float*)d_in[6];
  const float* upd_b1 = (const float*)d_in[7];
  const float* upd_w2 = (const float*)d_in[8];
  const float* upd_b2 = (const float*)d_in[9];
  const float* ln_g   = (const float*)d_in[10];
  const float* ln_b   = (const float*)d_in[11];

  prepack_w<<<384, 256, 0, stream>>>(msg_w1, msg_w2, upd_w1, upd_w2);
  gno_mfma<<<NB * (NN / TILE), NTHR, 0, stream>>>(
      h, coord, msg_w1, msg_b1, msg_b2, upd_b1, upd_b2, ln_g, ln_b,
      (float*)d_out);
}